// Round 4
// baseline (105.810 us; speedup 1.0000x reference)
//
#include <hip/hip_runtime.h>
#include <math.h>

#define Bz 2
#define Az 2
#define Cz 10
#define HWz 1024
#define Nz 2048              // HWz * Az
#define ACHW (Az*Cz*HWz)     // 20480
#define NBBOX (Bz*Az*7*HWz)  // 28672
#define NPP   (Bz*Cz*3*HWz)  // 61440
#define EPSf 1e-6f
#define LOG2E 1.4426950408889634f

#if __has_builtin(__builtin_amdgcn_exp2f)
#define EXP2F(x) __builtin_amdgcn_exp2f(x)
#else
#define EXP2F(x) exp2f(x)
#endif
#if __has_builtin(__builtin_amdgcn_rcpf)
#define RCPF(x) __builtin_amdgcn_rcpf(x)
#else
#define RCPF(x) (1.0f/(x))
#endif

static __device__ __forceinline__ unsigned short f2bf(float x) {
    unsigned u = __builtin_bit_cast(unsigned, x);
    unsigned r = (u + 0x7fffu + ((u >> 16) & 1u)) >> 16;
    return (unsigned short)r;
}

// wave64 sum via DPP on the VALU pipe. Total lands in lane 63.
#if __has_builtin(__builtin_amdgcn_update_dpp)
static __device__ __forceinline__ float wred(float x) {
    int t;
    t = __builtin_amdgcn_update_dpp(0, __builtin_bit_cast(int, x), 0x111, 0xf, 0xf, true);
    x += __builtin_bit_cast(float, t);   // row_shr:1
    t = __builtin_amdgcn_update_dpp(0, __builtin_bit_cast(int, x), 0x112, 0xf, 0xf, true);
    x += __builtin_bit_cast(float, t);   // row_shr:2
    t = __builtin_amdgcn_update_dpp(0, __builtin_bit_cast(int, x), 0x114, 0xf, 0xf, true);
    x += __builtin_bit_cast(float, t);   // row_shr:4
    t = __builtin_amdgcn_update_dpp(0, __builtin_bit_cast(int, x), 0x118, 0xf, 0xf, true);
    x += __builtin_bit_cast(float, t);   // row_shr:8
    t = __builtin_amdgcn_update_dpp(0, __builtin_bit_cast(int, x), 0x142, 0xa, 0xf, true);
    x += __builtin_bit_cast(float, t);   // row_bcast:15
    t = __builtin_amdgcn_update_dpp(0, __builtin_bit_cast(int, x), 0x143, 0xc, 0xf, true);
    x += __builtin_bit_cast(float, t);   // row_bcast:31 -> lane63 total
    return x;
}
#define WRED_LANE 63
#else
static __device__ __forceinline__ float wred(float x) {
    for (int off = 32; off > 0; off >>= 1) x += __shfl_down(x, off);
    return x;
}
#define WRED_LANE 0
#endif

static __device__ __forceinline__ float iou_e(float nx1,float ny1,float nx2,float ny2,float ar,
                                              float mx1,float my1,float mx2,float my2,float am) {
    float xx1 = fmaxf(nx1, mx1), yy1 = fmaxf(ny1, my1);
    float xx2 = fminf(nx2, mx2), yy2 = fminf(ny2, my2);
    float iw = fmaxf(xx2 - xx1, 0.f), ih = fmaxf(yy2 - yy1, 0.f);
    float inter = iw * ih;
    float uni = fmaxf(ar + am - inter, EPSf);
    return EXP2F(inter * LOG2E * RCPF(uni));   // exp2(iou*log2e)
}

// ws: LT float2[B*N] | RB float2[B*N] | GPQ uint2[B][C][HW] = {p1*log2e (f32), bf16(q0)|bf16(q1)<<16}

// ---- fused prep: passthrough copies + BEV + per-(b,c) softmax
__global__ __launch_bounds__(256) void k_pre(const float* __restrict__ scores,
                                             const float* __restrict__ bbox,
                                             const float* __restrict__ pp,
                                             const float* __restrict__ dec,
                                             float* __restrict__ out,
                                             float2* __restrict__ LT,
                                             float2* __restrict__ RB,
                                             uint2* __restrict__ GPQ) {
    int blk = blockIdx.x;
    int tid = threadIdx.x;
    __shared__ float red[256];

    if (blk < 240) {                    // copies
        int i = blk * 256 + tid;
        if (i < NBBOX) out[Bz*ACHW + i] = bbox[i];
        if (i < NPP)   out[Bz*ACHW + NBBOX + i] = pp[i];
        return;
    }
    if (blk < 256) {                    // BEV (4096 boxes)
        int i = (blk - 240) * 256 + tid;
        const float* d = dec + i*7;
        float x = d[0], y = d[1], dx = d[3], dy = d[4], yaw = d[6];
        const float PI = 3.14159265358979323846f;
        float normed = fabsf(yaw - floorf(yaw/PI + 0.5f) * PI);
        bool swp = normed > PI * 0.25f;
        float w = swp ? dy : dx;
        float h = swp ? dx : dy;
        LT[i] = make_float2(x - 0.5f*w, y - 0.5f*h);
        RB[i] = make_float2(x + 0.5f*w, y + 0.5f*h);
        return;
    }
    // softmax over n for (b,c)
    int bc = blk - 256;
    int b = bc / Cz, c = bc % Cz;
    const float* sbase = scores + b*ACHW;
    float vals[Nz/256];
    float mx = -INFINITY;
    #pragma unroll
    for (int j = 0; j < Nz/256; j++) {
        int n = tid + j*256;
        int a = n & 1, hw = n >> 1;
        float v = sbase[(a*Cz + c)*HWz + hw];
        vals[j] = v;
        mx = fmaxf(mx, v);
    }
    red[tid] = mx; __syncthreads();
    for (int s = 128; s > 0; s >>= 1) {
        if (tid < s) red[tid] = fmaxf(red[tid], red[tid+s]);
        __syncthreads();
    }
    mx = red[0]; __syncthreads();
    float sum = 0.f;
    #pragma unroll
    for (int j = 0; j < Nz/256; j++) {
        vals[j] = EXP2F((vals[j] - mx) * LOG2E);
        sum += vals[j];
    }
    red[tid] = sum; __syncthreads();
    for (int s = 128; s > 0; s >>= 1) {
        if (tid < s) red[tid] += red[tid+s];
        __syncthreads();
    }
    float inv = 1.f / red[0];
    const float* p1base = pp + b*Cz*3*HWz + (c*3 + 1)*HWz;
    uint2* gp = GPQ + (b*Cz + c)*HWz;
    #pragma unroll
    for (int j = 0; j < Nz/256; j++) {
        __syncthreads();
        red[tid] = vals[j] * inv;
        __syncthreads();
        if (tid < 128) {
            int hm = (j << 7) + tid;
            float q0 = red[2*tid], q1 = red[2*tid + 1];
            unsigned qq = (unsigned)f2bf(q0) | ((unsigned)f2bf(q1) << 16);
            float p1 = p1base[hm] * LOG2E;
            gp[hm] = make_uint2(__builtin_bit_cast(unsigned, p1), qq);
        }
    }
}

// ---- main: grid 1024 x 256thr. wave -> (hn, m-half). No LDS in main loop:
// boxes are L1-resident (32 KB), PQ streams through L1/L2 coalesced.
// Cross-wave (m-half pair) combine via tiny LDS scratch at the end.
__global__ __launch_bounds__(256, 4) void k_main(const float4* __restrict__ LT4,
                                                 const float4* __restrict__ RB4,
                                                 const uint2* __restrict__ GPQ,
                                                 const float* __restrict__ pp,
                                                 float* __restrict__ out) {
    __shared__ float SR[4][40];
    int tid = threadIdx.x;
    int wave = tid >> 6, lane = tid & 63;
    int bid = blockIdx.x;
    int b = bid >> 9;                 // 512 blocks per batch
    int blk = bid & 511;
    int hn = (blk << 1) + (wave >> 1);
    int mhalf = wave & 1;

    const float4* LTb = LT4 + (b << 10);
    const float4* RBb = RB4 + (b << 10);
    const uint2*  PQb = GPQ + b * (Cz * HWz);

    float4 bx = LTb[hn];               // lt of rows a=0,1
    float4 by = RBb[hn];               // rb
    float ar0 = (by.x - bx.x) * (by.y - bx.y);
    float ar1 = (by.z - bx.z) * (by.w - bx.w);

    float p0[Cz];
    const float* p0base = pp + b*(Cz*3*HWz) + hn;
    #pragma unroll
    for (int c = 0; c < Cz; c++) p0[c] = p0base[c * 3 * HWz];

    float l0[Cz], l1[Cz], a0[Cz], a1[Cz];
    #pragma unroll
    for (int c = 0; c < Cz; c++) { l0[c]=0.f; l1[c]=0.f; a0[c]=0.f; a1[c]=0.f; }

    int hm0 = (mhalf << 9) + lane;     // this wave's first hm
    for (int it = 0; it < 8; it++) {
        int hm = hm0 + (it << 6);
        float4 bl = LTb[hm];
        float4 br = RBb[hm];
        uint2 pqv[Cz];
        #pragma unroll
        for (int c = 0; c < Cz; c++) pqv[c] = PQb[(c << 10) + hm];

        float am0 = (br.x - bl.x) * (br.y - bl.y);
        float am1 = (br.z - bl.z) * (br.w - bl.w);
        float E00 = iou_e(bx.x,bx.y,by.x,by.y,ar0, bl.x,bl.y,br.x,br.y,am0);
        float E01 = iou_e(bx.x,bx.y,by.x,by.y,ar0, bl.z,bl.w,br.z,br.w,am1);
        float E10 = iou_e(bx.z,bx.w,by.z,by.w,ar1, bl.x,bl.y,br.x,br.y,am0);
        float E11 = iou_e(bx.z,bx.w,by.z,by.w,ar1, bl.z,bl.w,br.z,br.w,am1);
        float S0 = E00 + E01, S1 = E10 + E11;
        #pragma unroll
        for (int c = 0; c < Cz; c++) {
            uint2 pq = pqv[c];
            float p1 = __builtin_bit_cast(float, pq.x);
            float q0 = __builtin_bit_cast(float, pq.y << 16);
            float q1 = __builtin_bit_cast(float, pq.y & 0xffff0000u);
            float F = EXP2F(p0[c] * p1);
            l0[c] = fmaf(F, S0, l0[c]);
            l1[c] = fmaf(F, S1, l1[c]);
            float t0 = fmaf(E01, q1, E00 * q0);
            float t1 = fmaf(E11, q1, E10 * q0);
            a0[c] = fmaf(F, t0, a0[c]);
            a1[c] = fmaf(F, t1, a1[c]);
        }
    }

    #pragma unroll
    for (int c = 0; c < Cz; c++) {
        l0[c] = wred(l0[c]); l1[c] = wred(l1[c]);
        a0[c] = wred(a0[c]); a1[c] = wred(a1[c]);
    }
    if (lane == WRED_LANE) {
        #pragma unroll
        for (int c = 0; c < Cz; c++) {
            SR[wave][c]      = l0[c];
            SR[wave][10 + c] = l1[c];
            SR[wave][20 + c] = a0[c];
            SR[wave][30 + c] = a1[c];
        }
    }
    __syncthreads();
    if (tid < 40) {
        int p = tid / 20, rc = tid % 20;     // p: which hn of this block
        int row = rc / 10, c = rc % 10;      // row = anchor a
        int w0 = p << 1;
        float l = SR[w0][row*10 + c] + SR[w0+1][row*10 + c];
        float a = SR[w0][20 + row*10 + c] + SR[w0+1][20 + row*10 + c];
        out[b*ACHW + (row*Cz + c)*HWz + (blk << 1) + p] = a * RCPF(l);
    }
}

extern "C" void kernel_launch(void* const* d_in, const int* in_sizes, int n_in,
                              void* d_out, int out_size, void* d_ws, size_t ws_size,
                              hipStream_t stream) {
    const float* scores = (const float*)d_in[0];
    const float* bbox   = (const float*)d_in[1];
    const float* pp     = (const float*)d_in[2];
    const float* dec    = (const float*)d_in[3];
    float* out = (float*)d_out;

    float2* LT = (float2*)d_ws;
    float2* RB = LT + (size_t)Bz*Nz;
    uint2*  PQ = (uint2*)(RB + (size_t)Bz*Nz);

    hipLaunchKernelGGL(k_pre,  dim3(276),  dim3(256), 0, stream,
                       scores, bbox, pp, dec, out, LT, RB, PQ);
    hipLaunchKernelGGL(k_main, dim3(1024), dim3(256), 0, stream,
                       (const float4*)LT, (const float4*)RB, PQ, pp, out);
}

// Round 5
// 85.409 us; speedup vs baseline: 1.2389x; 1.2389x over previous
//
#include <hip/hip_runtime.h>
#include <math.h>

#define Bz 2
#define Az 2
#define Cz 10
#define HWz 1024
#define Nz 2048              // HWz * Az
#define ACHW (Az*Cz*HWz)     // 20480
#define NBBOX (Bz*Az*7*HWz)  // 28672
#define NPP   (Bz*Cz*3*HWz)  // 61440
#define EPSf 1e-6f
#define LOG2E 1.4426950408889634f

#if __has_builtin(__builtin_amdgcn_exp2f)
#define EXP2F(x) __builtin_amdgcn_exp2f(x)
#else
#define EXP2F(x) exp2f(x)
#endif
#if __has_builtin(__builtin_amdgcn_rcpf)
#define RCPF(x) __builtin_amdgcn_rcpf(x)
#else
#define RCPF(x) (1.0f/(x))
#endif

static __device__ __forceinline__ unsigned short f2bf(float x) {
    unsigned u = __builtin_bit_cast(unsigned, x);
    unsigned r = (u + 0x7fffu + ((u >> 16) & 1u)) >> 16;
    return (unsigned short)r;
}

static __device__ __forceinline__ float iou_e(float nx1,float ny1,float nx2,float ny2,float ar,
                                              float mx1,float my1,float mx2,float my2,float am) {
    float xx1 = fmaxf(nx1, mx1), yy1 = fmaxf(ny1, my1);
    float xx2 = fminf(nx2, mx2), yy2 = fminf(ny2, my2);
    float iw = fmaxf(xx2 - xx1, 0.f), ih = fmaxf(yy2 - yy1, 0.f);
    float inter = iw * ih;
    float uni = fmaxf(ar + am - inter, EPSf);
    return EXP2F(inter * LOG2E * RCPF(uni));   // exp2(iou*log2e)
}

// ws: LT float2[B*N] | RB float2[B*N] | GPQ2 uint2[B][HW][C] = {p1*log2e f32, bf16(q0)|bf16(q1)<<16}
//     | P float[512][2560] partials

// ---- fused prep: passthrough copies + BEV + per-(b,c) softmax
__global__ __launch_bounds__(256) void k_pre(const float* __restrict__ scores,
                                             const float* __restrict__ bbox,
                                             const float* __restrict__ pp,
                                             const float* __restrict__ dec,
                                             float* __restrict__ out,
                                             float2* __restrict__ LT,
                                             float2* __restrict__ RB,
                                             uint2* __restrict__ GPQ2) {
    int blk = blockIdx.x;
    int tid = threadIdx.x;
    __shared__ float red[256];

    if (blk < 240) {                    // copies
        int i = blk * 256 + tid;
        if (i < NBBOX) out[Bz*ACHW + i] = bbox[i];
        if (i < NPP)   out[Bz*ACHW + NBBOX + i] = pp[i];
        return;
    }
    if (blk < 256) {                    // BEV (4096 boxes)
        int i = (blk - 240) * 256 + tid;
        const float* d = dec + i*7;
        float x = d[0], y = d[1], dx = d[3], dy = d[4], yaw = d[6];
        const float PI = 3.14159265358979323846f;
        float normed = fabsf(yaw - floorf(yaw/PI + 0.5f) * PI);
        bool swp = normed > PI * 0.25f;
        float w = swp ? dy : dx;
        float h = swp ? dx : dy;
        LT[i] = make_float2(x - 0.5f*w, y - 0.5f*h);
        RB[i] = make_float2(x + 0.5f*w, y + 0.5f*h);
        return;
    }
    // softmax over n for (b,c)
    int bc = blk - 256;
    int b = bc / Cz, c = bc % Cz;
    const float* sbase = scores + b*ACHW;
    float vals[Nz/256];
    float mx = -INFINITY;
    #pragma unroll
    for (int j = 0; j < Nz/256; j++) {
        int n = tid + j*256;
        int a = n & 1, hw = n >> 1;
        float v = sbase[(a*Cz + c)*HWz + hw];
        vals[j] = v;
        mx = fmaxf(mx, v);
    }
    red[tid] = mx; __syncthreads();
    for (int s = 128; s > 0; s >>= 1) {
        if (tid < s) red[tid] = fmaxf(red[tid], red[tid+s]);
        __syncthreads();
    }
    mx = red[0]; __syncthreads();
    float sum = 0.f;
    #pragma unroll
    for (int j = 0; j < Nz/256; j++) {
        vals[j] = EXP2F((vals[j] - mx) * LOG2E);
        sum += vals[j];
    }
    red[tid] = sum; __syncthreads();
    for (int s = 128; s > 0; s >>= 1) {
        if (tid < s) red[tid] += red[tid+s];
        __syncthreads();
    }
    float inv = 1.f / red[0];
    const float* p1base = pp + b*Cz*3*HWz + (c*3 + 1)*HWz;
    uint2* gp = GPQ2 + (size_t)b*HWz*Cz;
    #pragma unroll
    for (int j = 0; j < Nz/256; j++) {
        __syncthreads();
        red[tid] = vals[j] * inv;
        __syncthreads();
        if (tid < 128) {
            int hm = (j << 7) + tid;
            float q0 = red[2*tid], q1 = red[2*tid + 1];
            unsigned qq = (unsigned)f2bf(q0) | ((unsigned)f2bf(q1) << 16);
            float p1 = p1base[hm] * LOG2E;
            gp[hm*Cz + c] = make_uint2(__builtin_bit_cast(unsigned, p1), qq);
        }
    }
}

// ---- main: 512 blocks x 256 thr. block = (b, hn-group g of 64, hm-slice sp of 64).
// lane = hn within group (n-side in registers); wave w handles 16 hm of the slice.
// m-side data staged once in LDS (7 KB), read via same-address broadcast.
// Partials P[bid][v*64+lane], v in [0,40): v<20 -> l(row*10+c), v>=20 -> acc.
__global__ __launch_bounds__(256, 2) void k_main(const float4* __restrict__ LT4,
                                                 const float4* __restrict__ RB4,
                                                 const uint2* __restrict__ GPQ2,
                                                 const float* __restrict__ pp,
                                                 float* __restrict__ P) {
    __shared__ __align__(16) char smem[40960];
    float4* SLT = (float4*)smem;                 // [64]
    float4* SRB = SLT + 64;                      // [64]
    uint2*  SPQ = (uint2*)(SRB + 64);            // [640]
    float*  RED = (float*)smem;                  // [4][64][40] (reused after loop)

    int tid = threadIdx.x;
    int wave = tid >> 6, lane = tid & 63;
    int bid = blockIdx.x;
    int b = bid >> 8;
    int r = bid & 255;
    int g = r >> 4, sp = r & 15;
    int hbase = sp << 6;

    const float4* LTb = LT4 + (b << 10);
    const float4* RBb = RB4 + (b << 10);
    const uint2*  Qb  = GPQ2 + (size_t)b*HWz*Cz + (size_t)hbase*Cz;

    // ---- stage m-side slice (64 hm) into LDS
    if (tid < 64)       SLT[tid] = LTb[hbase + tid];
    else if (tid < 128) SRB[tid - 64] = RBb[hbase + tid - 64];
    #pragma unroll
    for (int i = tid; i < 640; i += 256) SPQ[i] = Qb[i];

    // ---- n-side (per lane): boxes + p0
    int hn = (g << 6) + lane;
    float4 bx = LTb[hn], by = RBb[hn];
    float ar0 = (by.x - bx.x) * (by.y - bx.y);
    float ar1 = (by.z - bx.z) * (by.w - bx.w);
    float p0[Cz];
    const float* p0base = pp + b*(Cz*3*HWz) + hn;
    #pragma unroll
    for (int c = 0; c < Cz; c++) p0[c] = p0base[c * 3 * HWz];

    float l0[Cz], l1[Cz], a0[Cz], a1[Cz];
    #pragma unroll
    for (int c = 0; c < Cz; c++) { l0[c]=0.f; l1[c]=0.f; a0[c]=0.f; a1[c]=0.f; }

    __syncthreads();

    int j0 = wave << 4;
    #pragma unroll 4
    for (int i = 0; i < 16; i++) {
        int j = j0 + i;
        float4 bl = SLT[j];
        float4 br = SRB[j];
        float am0 = (br.x - bl.x) * (br.y - bl.y);
        float am1 = (br.z - bl.z) * (br.w - bl.w);
        float E00 = iou_e(bx.x,bx.y,by.x,by.y,ar0, bl.x,bl.y,br.x,br.y,am0);
        float E01 = iou_e(bx.x,bx.y,by.x,by.y,ar0, bl.z,bl.w,br.z,br.w,am1);
        float E10 = iou_e(bx.z,bx.w,by.z,by.w,ar1, bl.x,bl.y,br.x,br.y,am0);
        float E11 = iou_e(bx.z,bx.w,by.z,by.w,ar1, bl.z,bl.w,br.z,br.w,am1);
        float S0 = E00 + E01, S1 = E10 + E11;
        const uint2* pqrow = SPQ + j*Cz;
        #pragma unroll
        for (int c = 0; c < Cz; c++) {
            uint2 pq = pqrow[c];
            float p1 = __builtin_bit_cast(float, pq.x);
            float q0 = __builtin_bit_cast(float, pq.y << 16);
            float q1 = __builtin_bit_cast(float, pq.y & 0xffff0000u);
            float F = EXP2F(p0[c] * p1);
            l0[c] = fmaf(F, S0, l0[c]);
            l1[c] = fmaf(F, S1, l1[c]);
            float t0 = fmaf(E01, q1, E00 * q0);
            float t1 = fmaf(E11, q1, E10 * q0);
            a0[c] = fmaf(F, t0, a0[c]);
            a1[c] = fmaf(F, t1, a1[c]);
        }
    }

    __syncthreads();                     // all waves done reading staged data
    float* rw = RED + (wave*64 + lane)*40;
    #pragma unroll
    for (int c = 0; c < Cz; c++) {
        rw[c]      = l0[c];
        rw[10 + c] = l1[c];
        rw[20 + c] = a0[c];
        rw[30 + c] = a1[c];
    }
    __syncthreads();

    // sum the 4 waves' partials, write to P
    int vg = tid >> 6, ln = tid & 63;
    float* Pb = P + (size_t)bid * 2560;
    #pragma unroll
    for (int k = 0; k < 10; k++) {
        int v = vg + (k << 2);
        float s = RED[(0*64+ln)*40 + v] + RED[(1*64+ln)*40 + v]
                + RED[(2*64+ln)*40 + v] + RED[(3*64+ln)*40 + v];
        Pb[v*64 + ln] = s;
    }
}

// ---- reduce over the 16 hm-slices and finalize
__global__ __launch_bounds__(256) void k_red(const float* __restrict__ P,
                                             float* __restrict__ out) {
    int bg = blockIdx.x;                 // (b*16+g) in [0,32)
    int b = bg >> 4, g = bg & 15;
    const float* Pb = P + (size_t)bg * 16 * 2560;
    int tid = threadIdx.x;
    #pragma unroll
    for (int k = 0; k < 5; k++) {
        int pos = tid + (k << 8);        // [0,1280): v2*64+ln
        int v2 = pos >> 6, ln = pos & 63;
        float l = 0.f, a = 0.f;
        #pragma unroll
        for (int sp = 0; sp < 16; sp++) {
            const float* q = Pb + sp*2560;
            l += q[pos];
            a += q[1280 + pos];
        }
        int row = v2 / 10, c = v2 % 10;
        out[b*ACHW + (row*Cz + c)*HWz + (g << 6) + ln] = a * RCPF(l);
    }
}

extern "C" void kernel_launch(void* const* d_in, const int* in_sizes, int n_in,
                              void* d_out, int out_size, void* d_ws, size_t ws_size,
                              hipStream_t stream) {
    const float* scores = (const float*)d_in[0];
    const float* bbox   = (const float*)d_in[1];
    const float* pp     = (const float*)d_in[2];
    const float* dec    = (const float*)d_in[3];
    float* out = (float*)d_out;

    float2* LT = (float2*)d_ws;
    float2* RB = LT + (size_t)Bz*Nz;
    uint2*  PQ = (uint2*)(RB + (size_t)Bz*Nz);
    float*  P  = (float*)(PQ + (size_t)Bz*HWz*Cz);

    hipLaunchKernelGGL(k_pre,  dim3(276), dim3(256), 0, stream,
                       scores, bbox, pp, dec, out, LT, RB, PQ);
    hipLaunchKernelGGL(k_main, dim3(512), dim3(256), 0, stream,
                       (const float4*)LT, (const float4*)RB, PQ, pp, P);
    hipLaunchKernelGGL(k_red,  dim3(32),  dim3(256), 0, stream, P, out);
}